// Round 1
// baseline (281.639 us; speedup 1.0000x reference)
//
#include <hip/hip_runtime.h>

#define KK 32
#define INF 128
#define DD 64
#define OW 95   // 31 (row) + 64 (col)

__device__ __forceinline__ float wave_sum64(float v) {
#pragma unroll
    for (int m = 32; m; m >>= 1) v += __shfl_xor(v, m);
    return v;
}

// Kernel 1: z = h @ W_fc^T  plus per-node scalars aux[n] = (e_src, zw0, zw1, e_dst)
__global__ __launch_bounds__(256) void k_gemm(
    const float* __restrict__ h, const float* __restrict__ Wfc,
    const float* __restrict__ a_attn, const float* __restrict__ w_row,
    float* __restrict__ z, float4* __restrict__ aux)
{
    // wt4[ic][d] = W_fc[d][4ic..4ic+3]; reads are lane-contiguous -> conflict-free
    __shared__ float4 wt4[32][64];
    int t = threadIdx.x;
    for (int f = t; f < DD * (INF / 4); f += 256) {
        int d = f >> 5, ic = f & 31;
        wt4[ic][d] = reinterpret_cast<const float4*>(Wfc)[f];
    }
    __syncthreads();

    int lane = t & 63;
    int wave = t >> 6;
    float a0  = a_attn[lane];
    float a1  = a_attn[64 + lane];
    float wr0 = w_row[lane];
    float wr1 = w_row[64 + lane];

    int rowbase = blockIdx.x * 64 + wave * 16;
    for (int rr = 0; rr < 16; rr += 4) {
        int r = rowbase + rr;
        const float4* h0 = reinterpret_cast<const float4*>(h + (size_t)(r + 0) * INF);
        const float4* h1 = reinterpret_cast<const float4*>(h + (size_t)(r + 1) * INF);
        const float4* h2 = reinterpret_cast<const float4*>(h + (size_t)(r + 2) * INF);
        const float4* h3 = reinterpret_cast<const float4*>(h + (size_t)(r + 3) * INF);
        float acc0 = 0.f, acc1 = 0.f, acc2 = 0.f, acc3 = 0.f;
#pragma unroll 8
        for (int ic = 0; ic < 32; ++ic) {
            float4 w = wt4[ic][lane];
            float4 x0 = h0[ic], x1 = h1[ic], x2 = h2[ic], x3 = h3[ic];
            acc0 = fmaf(w.x, x0.x, fmaf(w.y, x0.y, fmaf(w.z, x0.z, fmaf(w.w, x0.w, acc0))));
            acc1 = fmaf(w.x, x1.x, fmaf(w.y, x1.y, fmaf(w.z, x1.z, fmaf(w.w, x1.w, acc1))));
            acc2 = fmaf(w.x, x2.x, fmaf(w.y, x2.y, fmaf(w.z, x2.z, fmaf(w.w, x2.w, acc2))));
            acc3 = fmaf(w.x, x3.x, fmaf(w.y, x3.y, fmaf(w.z, x3.z, fmaf(w.w, x3.w, acc3))));
        }
#pragma unroll
        for (int j = 0; j < 4; ++j) {
            float a = (j == 0) ? acc0 : (j == 1) ? acc1 : (j == 2) ? acc2 : acc3;
            z[(size_t)(r + j) * DD + lane] = a;
            float es  = wave_sum64(a * a0);
            float zw0 = wave_sum64(a * wr0);
            float zw1 = wave_sum64(a * wr1);
            float ed  = wave_sum64(a * a1);
            if (lane == 0) aux[r + j] = make_float4(es, zw0, zw1, ed);
        }
    }
}

// Kernel 2: per-node softmax + row/col convs (raw, pre-BN) + BN partial sums.
// One wave per destination node n; lane = d for the col part.
__global__ __launch_bounds__(256) void k_gat(
    const float* __restrict__ z, const float4* __restrict__ aux,
    const int* __restrict__ src_idx, const float* __restrict__ w_col,
    const float* __restrict__ b_row, const float* __restrict__ b_col,
    float* __restrict__ out, float4* __restrict__ partials)
{
    __shared__ float s_alpha[4][32];
    __shared__ int   s_src[4][32];
    __shared__ float4 s_part[4];

    int t = threadIdx.x, lane = t & 63, wave = t >> 6;
    int n = blockIdx.x * 4 + wave;

    int k = lane & 31;
    int sk = src_idx[(size_t)n * KK + k];

    // preload w_col column for this lane (8 KB, L1-resident)
    float wc[32];
#pragma unroll
    for (int kk = 0; kk < 32; ++kk) wc[kk] = w_col[kk * DD + lane];

    float rs = 0.f, rss = 0.f;
    if (lane < 32) {
        float4 ax = aux[sk];            // (e_src, zw0, zw1, e_dst) of source node
        float ed = aux[n].w;            // e_dst of this node (uniform)
        float e = ax.x + ed;
        e = e > 0.f ? e : 0.01f * e;    // leaky_relu
        float m = e;
#pragma unroll
        for (int s = 16; s; s >>= 1) m = fmaxf(m, __shfl_xor(m, s));
        float p = __expf(e - m);
        float sum = p;
#pragma unroll
        for (int s = 16; s; s >>= 1) sum += __shfl_xor(sum, s);
        float alpha = p / sum;
        s_alpha[wave][k] = alpha;
        s_src[wave][k] = sk;
        // row[k] = alpha_k * zw0[s_k] + alpha_{k+1} * zw1[s_{k+1}] + b_row
        float t1 = alpha * ax.z;
        float tn = __shfl_down(t1, 1);  // value of lane k+1 (k=31 unused)
        float rowv = fmaf(alpha, ax.y, tn) + b_row[0];
        if (k < 31) {
            out[(size_t)n * OW + k] = rowv;
            rs = rowv; rss = rowv * rowv;
        }
    }
    __syncthreads();

    // col[d] = sum_k alpha_k * w_col[k][d] * z[s_k][d]
    float acc = 0.f;
#pragma unroll
    for (int kk = 0; kk < 32; ++kk) {
        float al = s_alpha[wave][kk];
        int   s  = s_src[wave][kk];
        acc = fmaf(al * wc[kk], z[(size_t)s * DD + lane], acc);
    }
    float colv = acc + b_col[0];
    out[(size_t)n * OW + 31 + lane] = colv;

    // BN partial sums for this block
    float cs = colv, css = colv * colv;
    rs  = wave_sum64(rs);
    rss = wave_sum64(rss);
    cs  = wave_sum64(cs);
    css = wave_sum64(css);
    if (lane == 0) s_part[wave] = make_float4(rs, rss, cs, css);
    __syncthreads();
    if (t == 0) {
        float4 p0 = s_part[0], p1 = s_part[1], p2 = s_part[2], p3 = s_part[3];
        partials[blockIdx.x] = make_float4(p0.x + p1.x + p2.x + p3.x,
                                           p0.y + p1.y + p2.y + p3.y,
                                           p0.z + p1.z + p2.z + p3.z,
                                           p0.w + p1.w + p2.w + p3.w);
    }
}

// Kernel 3: reduce partials -> BN scale/bias (4 floats)
__global__ __launch_bounds__(256) void k_stats(
    const float4* __restrict__ partials, int nb,
    const float* __restrict__ g_row, const float* __restrict__ beta_row,
    const float* __restrict__ g_col, const float* __restrict__ beta_col,
    float* __restrict__ bnp, int N)
{
    __shared__ float4 sp[256];
    int t = threadIdx.x;
    float4 acc = make_float4(0.f, 0.f, 0.f, 0.f);
    for (int i = t; i < nb; i += 256) {
        float4 p = partials[i];
        acc.x += p.x; acc.y += p.y; acc.z += p.z; acc.w += p.w;
    }
    sp[t] = acc;
    __syncthreads();
    for (int s = 128; s > 0; s >>= 1) {
        if (t < s) {
            sp[t].x += sp[t + s].x; sp[t].y += sp[t + s].y;
            sp[t].z += sp[t + s].z; sp[t].w += sp[t + s].w;
        }
        __syncthreads();
    }
    if (t == 0) {
        float nrow = (float)N * 31.0f;
        float ncol = (float)N * 64.0f;
        float mr = sp[0].x / nrow;
        float vr = sp[0].y / nrow - mr * mr;
        float sr = g_row[0] / sqrtf(vr + 1e-5f);
        float br = beta_row[0] - mr * sr;
        float mc = sp[0].z / ncol;
        float vc = sp[0].w / ncol - mc * mc;
        float sc = g_col[0] / sqrtf(vc + 1e-5f);
        float bc = beta_col[0] - mc * sc;
        bnp[0] = sr; bnp[1] = br; bnp[2] = sc; bnp[3] = bc;
    }
}

// Kernel 4: in-place BN affine + ReLU over d_out
__global__ __launch_bounds__(256) void k_apply(
    float* __restrict__ out, const float* __restrict__ bnp, int total)
{
    float sr = bnp[0], br = bnp[1], sc = bnp[2], bc = bnp[3];
    int i = blockIdx.x * 256 + threadIdx.x;
    int stride = gridDim.x * 256;
    for (; i < total; i += stride) {
        int c = i % OW;
        float x = out[i];
        float y = (c < 31) ? fmaf(x, sr, br) : fmaf(x, sc, bc);
        out[i] = fmaxf(y, 0.0f);
    }
}

extern "C" void kernel_launch(void* const* d_in, const int* in_sizes, int n_in,
                              void* d_out, int out_size, void* d_ws, size_t ws_size,
                              hipStream_t stream) {
    const float* h        = (const float*)d_in[0];
    const float* Wfc      = (const float*)d_in[1];
    const float* a_attn   = (const float*)d_in[2];
    const float* w_row    = (const float*)d_in[3];
    const float* b_row    = (const float*)d_in[4];
    const float* w_col    = (const float*)d_in[5];
    const float* b_col    = (const float*)d_in[6];
    const float* g_row    = (const float*)d_in[7];
    const float* beta_row = (const float*)d_in[8];
    const float* g_col    = (const float*)d_in[9];
    const float* beta_col = (const float*)d_in[10];
    const int*   src_idx  = (const int*)d_in[11];

    int N = in_sizes[0] / INF;      // 65536
    float* out = (float*)d_out;

    // workspace layout
    float*  z        = (float*)d_ws;                     // N*64 f32 = 16 MB
    float4* aux      = (float4*)(z + (size_t)N * DD);    // N float4 = 1 MB
    float4* partials = aux + N;                          // N/4 float4 = 256 KB
    float*  bnp      = (float*)(partials + N / 4);       // 4 f32

    k_gemm <<<N / 64, 256, 0, stream>>>(h, Wfc, a_attn, w_row, z, aux);
    k_gat  <<<N / 4,  256, 0, stream>>>(z, aux, src_idx, w_col, b_row, b_col, out, partials);
    k_stats<<<1,      256, 0, stream>>>(partials, N / 4, g_row, beta_row, g_col, beta_col, bnp, N);
    int total = N * OW;
    k_apply<<<2048,   256, 0, stream>>>(out, bnp, total);
}

// Round 3
// 218.063 us; speedup vs baseline: 1.2916x; 1.2916x over previous
//
#include <hip/hip_runtime.h>
#include <hip/hip_bf16.h>

#define KK 32
#define INF 128
#define DD 64
#define OW 95   // 31 (row) + 64 (col)

__device__ __forceinline__ float bf2f(unsigned short u) {
    union { unsigned int i; float f; } cv; cv.i = (unsigned int)u << 16; return cv.f;
}

__device__ __forceinline__ float wave_sum64(float v) {
#pragma unroll
    for (int m = 32; m; m >>= 1) v += __shfl_xor(v, m);
    return v;
}

// Kernel 1: z = h @ W_fc^T, stored bf16. h tile in LDS (broadcast reads),
// W_fc row per lane in 128 VGPRs (lane = output dim d). No shuffles.
__global__ __launch_bounds__(256) void k_gemm(
    const float* __restrict__ h, const float* __restrict__ Wfc,
    __hip_bfloat16* __restrict__ zb)
{
    __shared__ float4 hs[2048];          // 64 rows x 32 float4 = 32 KB
    int t = threadIdx.x;
    int lane = t & 63, wave = t >> 6;

    // W row for this lane into registers
    float4 wreg[32];
    const float4* W4 = reinterpret_cast<const float4*>(Wfc) + (size_t)lane * 32;
#pragma unroll
    for (int i = 0; i < 32; ++i) wreg[i] = W4[i];

    size_t rowbase = (size_t)blockIdx.x * 64;
    const float4* h4 = reinterpret_cast<const float4*>(h) + rowbase * 32;
#pragma unroll
    for (int i = 0; i < 8; ++i) hs[t + 256 * i] = h4[t + 256 * i];
    __syncthreads();

    int r0 = wave * 16;
    for (int rr = 0; rr < 16; rr += 4) {
        int r = r0 + rr;
        float acc0 = 0.f, acc1 = 0.f, acc2 = 0.f, acc3 = 0.f;
#pragma unroll
        for (int ic = 0; ic < 32; ++ic) {
            float4 w = wreg[ic];
            float4 x0 = hs[(r + 0) * 32 + ic];
            float4 x1 = hs[(r + 1) * 32 + ic];
            float4 x2 = hs[(r + 2) * 32 + ic];
            float4 x3 = hs[(r + 3) * 32 + ic];
            acc0 = fmaf(w.x, x0.x, fmaf(w.y, x0.y, fmaf(w.z, x0.z, fmaf(w.w, x0.w, acc0))));
            acc1 = fmaf(w.x, x1.x, fmaf(w.y, x1.y, fmaf(w.z, x1.z, fmaf(w.w, x1.w, acc1))));
            acc2 = fmaf(w.x, x2.x, fmaf(w.y, x2.y, fmaf(w.z, x2.z, fmaf(w.w, x2.w, acc2))));
            acc3 = fmaf(w.x, x3.x, fmaf(w.y, x3.y, fmaf(w.z, x3.z, fmaf(w.w, x3.w, acc3))));
        }
        zb[(rowbase + r + 0) * DD + lane] = __float2bfloat16(acc0);
        zb[(rowbase + r + 1) * DD + lane] = __float2bfloat16(acc1);
        zb[(rowbase + r + 2) * DD + lane] = __float2bfloat16(acc2);
        zb[(rowbase + r + 3) * DD + lane] = __float2bfloat16(acc3);
    }
}

// Kernel 2: aux[n] = (e_src, zw0, zw1, e_dst) = z[n] @ [a0|wr0|wr1|a1].
// LDS-transpose reduce: thread (row, type) does a serial dot. No shuffles.
__global__ __launch_bounds__(256) void k_aux(
    const __hip_bfloat16* __restrict__ zb,
    const float* __restrict__ a_attn, const float* __restrict__ w_row,
    float* __restrict__ aux)
{
    __shared__ float zs[64][68];   // pad 68: 2-way max aliasing on reduce reads
    __shared__ float vec[4][68];
    int t = threadIdx.x;

    int i = t & 63, ty = t >> 6;
    vec[ty][i] = (ty == 0) ? a_attn[i]
               : (ty == 1) ? w_row[i]
               : (ty == 2) ? w_row[64 + i]
                           : a_attn[64 + i];

    size_t rowbase = (size_t)blockIdx.x * 64;
    const uint4* zb4 = reinterpret_cast<const uint4*>(zb + rowbase * DD); // 8 bf16 each
#pragma unroll
    for (int it = 0; it < 2; ++it) {
        int f = t + it * 256;              // [0,512): row = f>>3, chunk = f&7
        uint4 v = zb4[f];
        int row = f >> 3, c = (f & 7) * 8;
        zs[row][c + 0] = bf2f((unsigned short)(v.x & 0xffff));
        zs[row][c + 1] = bf2f((unsigned short)(v.x >> 16));
        zs[row][c + 2] = bf2f((unsigned short)(v.y & 0xffff));
        zs[row][c + 3] = bf2f((unsigned short)(v.y >> 16));
        zs[row][c + 4] = bf2f((unsigned short)(v.z & 0xffff));
        zs[row][c + 5] = bf2f((unsigned short)(v.z >> 16));
        zs[row][c + 6] = bf2f((unsigned short)(v.w & 0xffff));
        zs[row][c + 7] = bf2f((unsigned short)(v.w >> 16));
    }
    __syncthreads();

    int row = t >> 2, ty2 = t & 3;
    const float4* zr = reinterpret_cast<const float4*>(&zs[row][0]);
    const float4* vr = reinterpret_cast<const float4*>(&vec[ty2][0]);
    float s = 0.f;
#pragma unroll
    for (int q = 0; q < 16; ++q) {
        float4 a = zr[q], b = vr[q];
        s = fmaf(a.x, b.x, fmaf(a.y, b.y, fmaf(a.z, b.z, fmaf(a.w, b.w, s))));
    }
    aux[rowbase * 4 + t] = s;   // == (rowbase+row)*4 + ty2 : coalesced
}

// Kernel 3: per-node softmax + row/col convs (raw, pre-BN) + BN partials.
__global__ __launch_bounds__(256) void k_gat(
    const __hip_bfloat16* __restrict__ zb, const float4* __restrict__ aux,
    const int* __restrict__ src_idx, const float* __restrict__ w_col,
    const float* __restrict__ b_row, const float* __restrict__ b_col,
    float* __restrict__ out, float4* __restrict__ partials)
{
    __shared__ float s_alpha[4][32];
    __shared__ int   s_src[4][32];
    __shared__ float4 s_part[4];

    int t = threadIdx.x, lane = t & 63, wave = t >> 6;
    int n = blockIdx.x * 4 + wave;

    int k = lane & 31;
    int sk = src_idx[(size_t)n * KK + k];

    float wc[32];
#pragma unroll
    for (int kk = 0; kk < 32; ++kk) wc[kk] = w_col[kk * DD + lane];

    float rs = 0.f, rss = 0.f;
    if (lane < 32) {
        float4 ax = aux[sk];            // (e_src, zw0, zw1, e_dst) of source
        float ed = aux[n].w;            // e_dst of this node (uniform)
        float e = ax.x + ed;
        e = e > 0.f ? e : 0.01f * e;    // leaky_relu
        float m = e;
#pragma unroll
        for (int s = 16; s; s >>= 1) m = fmaxf(m, __shfl_xor(m, s));
        float p = __expf(e - m);
        float sum = p;
#pragma unroll
        for (int s = 16; s; s >>= 1) sum += __shfl_xor(sum, s);
        float alpha = p / sum;
        s_alpha[wave][k] = alpha;
        s_src[wave][k] = sk;
        float t1 = alpha * ax.z;
        float tn = __shfl_down(t1, 1);
        float rowv = fmaf(alpha, ax.y, tn) + b_row[0];
        if (k < 31) {
            out[(size_t)n * OW + k] = rowv;
            rs = rowv; rss = rowv * rowv;
        }
    }
    __syncthreads();

    const unsigned short* zu = (const unsigned short*)zb;
    float acc = 0.f;
#pragma unroll
    for (int kk = 0; kk < 32; ++kk) {
        float al = s_alpha[wave][kk];
        int   s  = s_src[wave][kk];
        acc = fmaf(al * wc[kk], bf2f(zu[(size_t)s * DD + lane]), acc);
    }
    float colv = acc + b_col[0];
    out[(size_t)n * OW + 31 + lane] = colv;

    float cs = colv, css = colv * colv;
    rs  = wave_sum64(rs);
    rss = wave_sum64(rss);
    cs  = wave_sum64(cs);
    css = wave_sum64(css);
    if (lane == 0) s_part[wave] = make_float4(rs, rss, cs, css);
    __syncthreads();
    if (t == 0) {
        float4 p0 = s_part[0], p1 = s_part[1], p2 = s_part[2], p3 = s_part[3];
        partials[blockIdx.x] = make_float4(p0.x + p1.x + p2.x + p3.x,
                                           p0.y + p1.y + p2.y + p3.y,
                                           p0.z + p1.z + p2.z + p3.z,
                                           p0.w + p1.w + p2.w + p3.w);
    }
}

// Kernel 4: reduce partials -> BN scale/bias (4 floats)
__global__ __launch_bounds__(256) void k_stats(
    const float4* __restrict__ partials, int nb,
    const float* __restrict__ g_row, const float* __restrict__ beta_row,
    const float* __restrict__ g_col, const float* __restrict__ beta_col,
    float* __restrict__ bnp, int N)
{
    __shared__ float4 sp[256];
    int t = threadIdx.x;
    float4 acc = make_float4(0.f, 0.f, 0.f, 0.f);
    for (int i = t; i < nb; i += 256) {
        float4 p = partials[i];
        acc.x += p.x; acc.y += p.y; acc.z += p.z; acc.w += p.w;
    }
    sp[t] = acc;
    __syncthreads();
    for (int s = 128; s > 0; s >>= 1) {
        if (t < s) {
            sp[t].x += sp[t + s].x; sp[t].y += sp[t + s].y;
            sp[t].z += sp[t + s].z; sp[t].w += sp[t + s].w;
        }
        __syncthreads();
    }
    if (t == 0) {
        float nrow = (float)N * 31.0f;
        float ncol = (float)N * 64.0f;
        float mr = sp[0].x / nrow;
        float vr = sp[0].y / nrow - mr * mr;
        float sr = g_row[0] / sqrtf(vr + 1e-5f);
        float br = beta_row[0] - mr * sr;
        float mc = sp[0].z / ncol;
        float vc = sp[0].w / ncol - mc * mc;
        float sc = g_col[0] / sqrtf(vc + 1e-5f);
        float bc = beta_col[0] - mc * sc;
        bnp[0] = sr; bnp[1] = br; bnp[2] = sc; bnp[3] = bc;
    }
}

// Kernel 5: in-place BN affine + ReLU over d_out
__global__ __launch_bounds__(256) void k_apply(
    float* __restrict__ out, const float* __restrict__ bnp, int total)
{
    float sr = bnp[0], br = bnp[1], sc = bnp[2], bc = bnp[3];
    int i = blockIdx.x * 256 + threadIdx.x;
    int stride = gridDim.x * 256;
    for (; i < total; i += stride) {
        int c = i % OW;
        float x = out[i];
        float y = (c < 31) ? fmaf(x, sr, br) : fmaf(x, sc, bc);
        out[i] = fmaxf(y, 0.0f);
    }
}

extern "C" void kernel_launch(void* const* d_in, const int* in_sizes, int n_in,
                              void* d_out, int out_size, void* d_ws, size_t ws_size,
                              hipStream_t stream) {
    const float* h        = (const float*)d_in[0];
    const float* Wfc      = (const float*)d_in[1];
    const float* a_attn   = (const float*)d_in[2];
    const float* w_row    = (const float*)d_in[3];
    const float* b_row    = (const float*)d_in[4];
    const float* w_col    = (const float*)d_in[5];
    const float* b_col    = (const float*)d_in[6];
    const float* g_row    = (const float*)d_in[7];
    const float* beta_row = (const float*)d_in[8];
    const float* g_col    = (const float*)d_in[9];
    const float* beta_col = (const float*)d_in[10];
    const int*   src_idx  = (const int*)d_in[11];

    int N = in_sizes[0] / INF;      // 65536
    float* out = (float*)d_out;

    // workspace layout
    __hip_bfloat16* zb = (__hip_bfloat16*)d_ws;                 // N*64 bf16 = 8 MB
    float4* aux      = (float4*)((char*)d_ws + (size_t)N * DD * 2);  // N float4 = 1 MB
    float4* partials = aux + N;                                 // N/4 float4 = 256 KB
    float*  bnp      = (float*)(partials + N / 4);              // 4 f32

    k_gemm <<<N / 64, 256, 0, stream>>>(h, Wfc, zb);
    k_aux  <<<N / 64, 256, 0, stream>>>(zb, a_attn, w_row, (float*)aux);
    k_gat  <<<N / 4,  256, 0, stream>>>(zb, aux, src_idx, w_col, b_row, b_col, out, partials);
    k_stats<<<1,      256, 0, stream>>>(partials, N / 4, g_row, beta_row, g_col, beta_col, bnp, N);
    int total = N * OW;
    k_apply<<<2048,   256, 0, stream>>>(out, bnp, total);
}

// Round 4
// 172.699 us; speedup vs baseline: 1.6308x; 1.2627x over previous
//
#include <hip/hip_runtime.h>
#include <hip/hip_bf16.h>

#define KK 32
#define INF 128
#define DD 64
#define OW 95   // 31 (row) + 64 (col)

typedef __attribute__((ext_vector_type(8))) short s8v;    // 8 bf16 (4 VGPR)
typedef __attribute__((ext_vector_type(4))) float f32x4;  // MFMA accumulator

__device__ __forceinline__ float bf2f(unsigned short u) {
    union { unsigned int i; float f; } cv; cv.i = (unsigned int)u << 16; return cv.f;
}
__device__ __forceinline__ unsigned short f2bf(float f) {
    __hip_bfloat16 h = __float2bfloat16(f);
    return *reinterpret_cast<unsigned short*>(&h);
}
__device__ __forceinline__ s8v pack8(float4 a, float4 b) {
    union { unsigned short u[8]; s8v v; } r;
    r.u[0] = f2bf(a.x); r.u[1] = f2bf(a.y); r.u[2] = f2bf(a.z); r.u[3] = f2bf(a.w);
    r.u[4] = f2bf(b.x); r.u[5] = f2bf(b.y); r.u[6] = f2bf(b.z); r.u[7] = f2bf(b.w);
    return r.v;
}

// Kernel 1: z = h @ W_fc^T via MFMA bf16; writes zb (bf16) + aux[n] =
// (z.a0, z.wr0, z.wr1, z.a1) computed from the LDS z-tile (k_aux fused).
// Block: 256 thr = 4 waves; 64 rows x 64 d per block; wave = 16-row stripe.
__global__ __launch_bounds__(256) void k_gemm(
    const float* __restrict__ h, const float* __restrict__ Wfc,
    const float* __restrict__ a_attn, const float* __restrict__ w_row,
    __hip_bfloat16* __restrict__ zb, float* __restrict__ aux)
{
    __shared__ __align__(16) unsigned short zs[64][72];  // 144 B rows (16B-aligned)
    __shared__ float vec[4][68];

    int t = threadIdx.x, lane = t & 63, wave = t >> 6;
    int g = lane >> 4, c = lane & 15;
    size_t rowbase = (size_t)blockIdx.x * 64;

    {   // stage the 4 reduction vectors for the aux epilogue
        int i = t & 63, ty = t >> 6;
        vec[ty][i] = (ty == 0) ? a_attn[i]
                   : (ty == 1) ? w_row[i]
                   : (ty == 2) ? w_row[64 + i]
                               : a_attn[64 + i];
    }

    // A fragments: m = c (lane&15), k = kt*32 + g*8 + j
    const float* hrow = h + (rowbase + (size_t)wave * 16 + c) * INF;
    s8v afr[4];
#pragma unroll
    for (int kt = 0; kt < 4; ++kt) {
        const float* p = hrow + kt * 32 + g * 8;
        afr[kt] = pack8(*(const float4*)p, *(const float4*)(p + 4));
    }
    // B fragments: n = nt*16 + c, same k mapping (symmetric with A)
    s8v bfr[4][4];
#pragma unroll
    for (int nt = 0; nt < 4; ++nt) {
        const float* wrow = Wfc + (size_t)(nt * 16 + c) * INF;
#pragma unroll
        for (int kt = 0; kt < 4; ++kt) {
            const float* p = wrow + kt * 32 + g * 8;
            bfr[nt][kt] = pack8(*(const float4*)p, *(const float4*)(p + 4));
        }
    }

    f32x4 acc[4];
#pragma unroll
    for (int nt = 0; nt < 4; ++nt) {
        acc[nt] = (f32x4){0.f, 0.f, 0.f, 0.f};
#pragma unroll
        for (int kt = 0; kt < 4; ++kt)
            acc[nt] = __builtin_amdgcn_mfma_f32_16x16x32_bf16(afr[kt], bfr[nt][kt], acc[nt], 0, 0, 0);
    }

    // C/D layout (HW-verified): col = lane&15, row = (lane>>4)*4 + reg
#pragma unroll
    for (int nt = 0; nt < 4; ++nt)
#pragma unroll
        for (int r = 0; r < 4; ++r)
            zs[wave * 16 + g * 4 + r][nt * 16 + c] = f2bf(acc[nt][r]);
    __syncthreads();

    // coalesced stream LDS -> zb (64 rows x 128 B)
#pragma unroll
    for (int it = 0; it < 2; ++it) {
        int f = t + it * 256;          // [0,512): row = f>>3, 16B chunk = f&7
        int row = f >> 3, ch = f & 7;
        uint4 v = *(const uint4*)((const char*)&zs[row][0] + ch * 16);
        *(uint4*)((char*)zb + (rowbase + row) * 128 + ch * 16) = v;
    }

    // aux: thread (row, ty) serial dot over 64 dims
    {
        int row = t >> 2, ty = t & 3;
        const uint4* zr = (const uint4*)&zs[row][0];
        float s = 0.f;
#pragma unroll
        for (int q = 0; q < 8; ++q) {
            uint4 v = zr[q];
            const float* vp = &vec[ty][q * 8];
            s = fmaf(bf2f((unsigned short)(v.x & 0xffff)), vp[0], s);
            s = fmaf(bf2f((unsigned short)(v.x >> 16)),    vp[1], s);
            s = fmaf(bf2f((unsigned short)(v.y & 0xffff)), vp[2], s);
            s = fmaf(bf2f((unsigned short)(v.y >> 16)),    vp[3], s);
            s = fmaf(bf2f((unsigned short)(v.z & 0xffff)), vp[4], s);
            s = fmaf(bf2f((unsigned short)(v.z >> 16)),    vp[5], s);
            s = fmaf(bf2f((unsigned short)(v.w & 0xffff)), vp[6], s);
            s = fmaf(bf2f((unsigned short)(v.w >> 16)),    vp[7], s);
        }
        aux[rowbase * 4 + t] = s;      // == (rowbase+row)*4 + ty : coalesced
    }
}

// Kernel 2: softmax + row/col convs + BN partials. Wave = 2 nodes (both
// 32-lane halves active). Col loop: lane = (half, d-pair), dword gathers.
__global__ __launch_bounds__(256) void k_gat(
    const unsigned short* __restrict__ zb, const float4* __restrict__ aux,
    const int* __restrict__ src_idx, const float* __restrict__ w_col,
    const float* __restrict__ b_row, const float* __restrict__ b_col,
    float* __restrict__ out, float4* __restrict__ partials)
{
    __shared__ float        s_alpha[4][2][32];
    __shared__ unsigned int s_soff[4][2][32];
    __shared__ float        s_wc[2048];       // w_col [32][64]
    __shared__ float4       s_part[8];

    int t = threadIdx.x, lane = t & 63, wave = t >> 6;
    int half = lane >> 5, hk = lane & 31;
    int n = blockIdx.x * 8 + wave * 2 + half;

#pragma unroll
    for (int i = 0; i < 8; ++i) s_wc[t + 256 * i] = w_col[t + 256 * i];

    const float* auxf = (const float*)aux;
    int sk = src_idx[(size_t)n * KK + hk];
    float4 ax = aux[sk];                 // (e_src, zw0, zw1, e_dst) of source
    float ed = auxf[n * 4 + 3];          // e_dst of this node
    float e = ax.x + ed;
    e = e > 0.f ? e : 0.01f * e;         // leaky_relu
    float m = e;
#pragma unroll
    for (int s = 16; s; s >>= 1) m = fmaxf(m, __shfl_xor(m, s));   // stays in half
    float p = __expf(e - m);
    float sum = p;
#pragma unroll
    for (int s = 16; s; s >>= 1) sum += __shfl_xor(sum, s);
    float alpha = p / sum;
    s_alpha[wave][half][hk] = alpha;
    s_soff[wave][half][hk] = (unsigned int)sk * 128u;   // byte offset of z row
    float t1 = alpha * ax.z;
    float tn = __shfl_down(t1, 1);       // hk=31 result unused
    float rowv = fmaf(alpha, ax.y, tn) + b_row[0];
    float rs = 0.f, rss = 0.f;
    if (hk < 31) {
        out[(size_t)n * OW + hk] = rowv;
        rs = rowv; rss = rowv * rowv;
    }
    __syncthreads();

    const char* zbase = (const char*)zb;
    float acc0 = 0.f, acc1 = 0.f;
    int wbase = wave, hbase = half;
    unsigned int dof = (unsigned int)hk * 4u;   // this lane's d-pair byte offset
#pragma unroll
    for (int kk = 0; kk < 32; ++kk) {
        float al = s_alpha[wbase][hbase][kk];
        unsigned int so = s_soff[wbase][hbase][kk];
        unsigned int zv = *(const unsigned int*)(zbase + (size_t)(so + dof));
        float2 wcp = *(const float2*)&s_wc[kk * 64 + hk * 2];
        union { unsigned int u; float f; } lo, hi;
        lo.u = zv << 16;               // d = 2*hk
        hi.u = zv & 0xffff0000u;       // d = 2*hk+1
        acc0 = fmaf(al * wcp.x, lo.f, acc0);
        acc1 = fmaf(al * wcp.y, hi.f, acc1);
    }
    float bc = b_col[0];
    float colv0 = acc0 + bc, colv1 = acc1 + bc;
    out[(size_t)n * OW + 31 + 2 * hk] = colv0;
    out[(size_t)n * OW + 32 + 2 * hk] = colv1;

    float cs = colv0 + colv1, css = colv0 * colv0 + colv1 * colv1;
#pragma unroll
    for (int s = 16; s; s >>= 1) {
        rs  += __shfl_xor(rs, s);
        rss += __shfl_xor(rss, s);
        cs  += __shfl_xor(cs, s);
        css += __shfl_xor(css, s);
    }
    if (hk == 0) s_part[wave * 2 + half] = make_float4(rs, rss, cs, css);
    __syncthreads();
    if (t == 0) {
        float4 a = make_float4(0.f, 0.f, 0.f, 0.f);
#pragma unroll
        for (int i = 0; i < 8; ++i) {
            a.x += s_part[i].x; a.y += s_part[i].y;
            a.z += s_part[i].z; a.w += s_part[i].w;
        }
        partials[blockIdx.x] = a;
    }
}

// Kernel 3: reduce partials -> BN scale/bias (4 floats)
__global__ __launch_bounds__(256) void k_stats(
    const float4* __restrict__ partials, int nb,
    const float* __restrict__ g_row, const float* __restrict__ beta_row,
    const float* __restrict__ g_col, const float* __restrict__ beta_col,
    float* __restrict__ bnp, int N)
{
    __shared__ float4 sp[256];
    int t = threadIdx.x;
    float4 acc = make_float4(0.f, 0.f, 0.f, 0.f);
    for (int i = t; i < nb; i += 256) {
        float4 p = partials[i];
        acc.x += p.x; acc.y += p.y; acc.z += p.z; acc.w += p.w;
    }
    sp[t] = acc;
    __syncthreads();
    for (int s = 128; s > 0; s >>= 1) {
        if (t < s) {
            sp[t].x += sp[t + s].x; sp[t].y += sp[t + s].y;
            sp[t].z += sp[t + s].z; sp[t].w += sp[t + s].w;
        }
        __syncthreads();
    }
    if (t == 0) {
        float nrow = (float)N * 31.0f;
        float ncol = (float)N * 64.0f;
        float mr = sp[0].x / nrow;
        float vr = sp[0].y / nrow - mr * mr;
        float sr = g_row[0] / sqrtf(vr + 1e-5f);
        float br = beta_row[0] - mr * sr;
        float mc = sp[0].z / ncol;
        float vc = sp[0].w / ncol - mc * mc;
        float sc = g_col[0] / sqrtf(vc + 1e-5f);
        float bc = beta_col[0] - mc * sc;
        bnp[0] = sr; bnp[1] = br; bnp[2] = sc; bnp[3] = bc;
    }
}

// Kernel 4: in-place BN affine + ReLU over d_out
__global__ __launch_bounds__(256) void k_apply(
    float* __restrict__ out, const float* __restrict__ bnp, int total)
{
    float sr = bnp[0], br = bnp[1], sc = bnp[2], bc = bnp[3];
    int i = blockIdx.x * 256 + threadIdx.x;
    int stride = gridDim.x * 256;
    for (; i < total; i += stride) {
        int c = i % OW;
        float x = out[i];
        float y = (c < 31) ? fmaf(x, sr, br) : fmaf(x, sc, bc);
        out[i] = fmaxf(y, 0.0f);
    }
}

extern "C" void kernel_launch(void* const* d_in, const int* in_sizes, int n_in,
                              void* d_out, int out_size, void* d_ws, size_t ws_size,
                              hipStream_t stream) {
    const float* h        = (const float*)d_in[0];
    const float* Wfc      = (const float*)d_in[1];
    const float* a_attn   = (const float*)d_in[2];
    const float* w_row    = (const float*)d_in[3];
    const float* b_row    = (const float*)d_in[4];
    const float* w_col    = (const float*)d_in[5];
    const float* b_col    = (const float*)d_in[6];
    const float* g_row    = (const float*)d_in[7];
    const float* beta_row = (const float*)d_in[8];
    const float* g_col    = (const float*)d_in[9];
    const float* beta_col = (const float*)d_in[10];
    const int*   src_idx  = (const int*)d_in[11];

    int N = in_sizes[0] / INF;      // 65536
    float* out = (float*)d_out;

    // workspace layout
    __hip_bfloat16* zb = (__hip_bfloat16*)d_ws;                      // 8 MB
    float4* aux      = (float4*)((char*)d_ws + (size_t)N * DD * 2);  // 1 MB
    float4* partials = aux + N;                                      // N/8 float4
    float*  bnp      = (float*)(partials + N / 8);

    k_gemm <<<N / 64, 256, 0, stream>>>(h, Wfc, a_attn, w_row, zb, (float*)aux);
    k_gat  <<<N / 8,  256, 0, stream>>>((const unsigned short*)zb, aux, src_idx,
                                        w_col, b_row, b_col, out, partials);
    k_stats<<<1,      256, 0, stream>>>(partials, N / 8, g_row, beta_row, g_col, beta_col, bnp, N);
    int total = N * OW;
    k_apply<<<2048,   256, 0, stream>>>(out, bnp, total);
}